// Round 1
// baseline (18007.109 us; speedup 1.0000x reference)
//
#include <hip/hip_runtime.h>

typedef unsigned int u32;
typedef unsigned long long u64;
typedef unsigned short u16;
typedef __attribute__((ext_vector_type(8))) short short8;
typedef __attribute__((ext_vector_type(4))) float f32x4;

#define MFMA(a,b,c) __builtin_amdgcn_mfma_f32_16x16x32_bf16((a),(b),(c),0,0,0)

__device__ __forceinline__ float bf2f(u32 b){ union{u32 u; float f;} v; v.u = b<<16; return v.f; }
__device__ __forceinline__ u16 f2bf(float f){ union{float f; u32 u;} v; v.f = f; u32 u = v.u;
  return (u16)((u + 0x7fffu + ((u>>16)&1u)) >> 16); }
__device__ __forceinline__ u32 pack_f(float v){
  u16 hi = f2bf(v); u16 lo = f2bf(v - bf2f(hi)); return (u32)hi | ((u32)lo<<16); }

__device__ __forceinline__ void unpack8(uint4 a, uint4 b, short8& hi, short8& lo){
  u32 w[8] = {a.x,a.y,a.z,a.w,b.x,b.y,b.z,b.w};
#pragma unroll
  for (int j=0;j<8;++j){ hi[j] = (short)(w[j] & 0xffffu); lo[j] = (short)(w[j] >> 16); }
}
__device__ __forceinline__ void unpackq(u64 q0,u64 q1,u64 q2,u64 q3, short8& hi, short8& lo){
  u32 w[8] = {(u32)q0,(u32)(q0>>32),(u32)q1,(u32)(q1>>32),(u32)q2,(u32)(q2>>32),(u32)q3,(u32)(q3>>32)};
#pragma unroll
  for (int j=0;j<8;++j){ hi[j] = (short)(w[j] & 0xffffu); lo[j] = (short)(w[j] >> 16); }
}

// ---------------- workspace layout (bytes) ----------------
constexpr size_t OFF_Y    = 0;            // u32[1000][32][256] = 32,768,000 ; reused as out2 [250][32][1024]
constexpr size_t OFF_SUB  = 32768000;     // u32[250][32][1024] = 32,768,000
constexpr size_t OFF_W0XH = 65536000;     // u16[256*3072]  frag layout
constexpr size_t OFF_W0XL = 67108864;
constexpr size_t OFF_W0HH = 68681728;     // u16[1024*3072] frag layout
constexpr size_t OFF_W0HL = 74973184;
constexpr size_t OFF_W1XH = 81264640;
constexpr size_t OFF_W1XL = 87556096;
constexpr size_t OFF_W1HH = 93847552;
constexpr size_t OFF_W1HL = 100139008;
constexpr size_t OFF_HB0  = 106430464;    // u32[3][32][1024]
constexpr size_t OFF_HB1  = 106823680;
constexpr size_t OFF_FL0  = 107216896;    // int[64] (padded 1KB)
constexpr size_t OFF_FL1  = 107217920;
constexpr size_t WS_NEED  = 107218944;

// ---------------- weight fragment builder ----------------
// layout: [wg=64][kq=4][nt=3][kt=K/128][lane=64][8]
// element: k = kq*(K/4) + kt*32 + (lane>>4)*8 + j ; col = nt*1024 + wg*16 + (lane&15)
__global__ void build_frags(const float* __restrict__ W, u16* __restrict__ fhi,
                            u16* __restrict__ flo, int K){
  const int KT = K >> 7;
  const int KQ4 = K >> 2;
  size_t total = (size_t)K * 3072;
  for (size_t i = (size_t)blockIdx.x*blockDim.x + threadIdx.x; i < total;
       i += (size_t)gridDim.x*blockDim.x){
    int j = (int)(i & 7); size_t r = i >> 3;
    int l = (int)(r & 63); r >>= 6;
    int kt = (int)(r % KT); r /= KT;
    int nt = (int)(r % 3); r /= 3;
    int kq = (int)(r & 3); r >>= 2;
    int wg = (int)r;
    int k = kq*KQ4 + kt*32 + ((l>>4)<<3) + j;
    int col = nt*1024 + wg*16 + (l&15);
    float v = W[(size_t)k*3072 + col];
    u16 hi = f2bf(v);
    u16 lo = f2bf(v - bf2f(hi));
    fhi[i] = hi; flo[i] = lo;
  }
}

// ---------------- init h0 + flags ----------------
__global__ void init_state(const float* __restrict__ h0, u32* hb0, u32* hb1,
                           int* f0, int* f1){
  int i = blockIdx.x*blockDim.x + threadIdx.x;
  if (i < 64){ f0[i]=0; f1[i]=0; }
  if (i < 32768){
    int uu = i & 1023;
    hb0[i] = pack_f(h0[uu]);
    hb1[i] = 0u;
  }
}

// ---------------- conv + relu + pack ----------------
// x [32][1000][256] f32 -> yp [1000][32][256] packed {bf16hi, bf16lo}
__global__ void conv_pack(const float* __restrict__ x, const float* __restrict__ cw,
                          u32* __restrict__ yp){
  for (size_t i = (size_t)blockIdx.x*blockDim.x + threadIdx.x; i < 8192000ull;
       i += (size_t)gridDim.x*blockDim.x){
    int f = (int)(i & 255); int b = (int)((i>>8)&31); int t = (int)(i>>13);
    const float* xb = x + ((size_t)b*1000 + t)*256 + f;
    float acc = xb[0]*cw[256+f];
    if (t > 0)   acc += xb[-256]*cw[f];
    if (t < 999) acc += xb[256]*cw[512+f];
    acc = fmaxf(acc, 0.0f);
    yp[i] = pack_f(acc);
  }
}

// ---------------- persistent GRU layer ----------------
// 64 WGs x 512 threads (8 waves). WG owns 16 units (48 gate cols).
// wave role: m = wave&1 (batch tile), kq = wave>>1 (K quarter).
template<int LAYER>
__global__ __launch_bounds__(512, 1)
void gru_persist(const u32* __restrict__ xin,
                 const u16* __restrict__ wx_hi, const u16* __restrict__ wx_lo,
                 const u16* __restrict__ wh_hi, const u16* __restrict__ wh_lo,
                 const float* __restrict__ bias,
                 u32* hbuf, int* flags, u32* out_pack)
{
  constexpr int T   = (LAYER==0) ? 1000 : 250;
  constexpr int KX  = (LAYER==0) ? 256 : 1024;
  constexpr int KTX = KX >> 7;           // ktiles per quarter: 2 or 8
  __shared__ u16 Brec[4*3*8*512];                       // 96KB: Wh-hi slice
  __shared__ u16 Bx[(LAYER==0) ? (4*3*2*512) : 8];      // 24KB layer0 Wx-hi slice
  __shared__ float exch[4*4*32*16];                     // 32KB gate exchange
  __shared__ float harr[512];                           // own h (fp32)

  const int tid  = threadIdx.x;
  const int wg   = blockIdx.x;
  const int lane = tid & 63;
  const int wave = tid >> 6;
  const int m    = wave & 1;
  const int kq   = wave >> 1;
  const int u0   = wg * 16;

  { // stage Whi (and layer0 Wx-hi) into LDS
    const uint4* s = (const uint4*)(wh_hi + (size_t)wg*(4*3*8*512));
    uint4* d = (uint4*)Brec;
    for (int i = tid; i < (4*3*8*512)/8; i += 512) d[i] = s[i];
    if (LAYER==0){
      const uint4* s2 = (const uint4*)(wx_hi + (size_t)wg*(4*3*KTX*512));
      uint4* d2 = (uint4*)Bx;
      for (int i = tid; i < (4*3*KTX*512)/8; i += 512) d2[i] = s2[i];
    }
    u32 p = hbuf[(tid>>4)*1024 + u0 + (tid&15)];
    harr[tid] = bf2f(p & 0xffffu) + bf2f(p >> 16);
  }
  __syncthreads();

  // elementwise-role constants
  const int eb = tid >> 4, eul = tid & 15, eu = u0 + eul;
  const float zb  = bias[eu]        + bias[3072 + eu];
  const float rb  = bias[1024 + eu] + bias[4096 + eu];
  const float hxb = bias[2048 + eu];
  const float hrb = bias[5120 + eu];

  // wave-role constants
  const int arow = 16*m + (lane & 15);
  const int kseg = (lane >> 4) << 3;
  const u16* wxhi_b = wx_hi + ((size_t)(wg*4 + kq)*3*KTX)*512 + lane*8;
  const u16* wxlo_b = wx_lo + ((size_t)(wg*4 + kq)*3*KTX)*512 + lane*8;
  const u16* whlo_b = wh_lo + ((size_t)(wg*4 + kq)*3*8)*512 + lane*8;

  int cur = 0;
  for (int t = 0; t < T; ++t) {
    const int nxt = (t+1) % 3;
    f32x4 xacc[3], racc[3];
#pragma unroll
    for (int nt=0; nt<3; ++nt){
      xacc[nt] = (f32x4){0.f,0.f,0.f,0.f};
      racc[nt] = (f32x4){0.f,0.f,0.f,0.f};
    }
    { // fused xproj: xin[t] (32 x KX) @ Wx slice
      const u32* xrow = xin + ((size_t)t*32 + arow)*KX + kq*(KX>>2) + kseg;
#pragma unroll 2
      for (int kt = 0; kt < KTX; ++kt) {
        uint4 a0 = *(const uint4*)(xrow + kt*32);
        uint4 a1 = *(const uint4*)(xrow + kt*32 + 4);
        short8 ahi, alo; unpack8(a0, a1, ahi, alo);
#pragma unroll
        for (int nt = 0; nt < 3; ++nt) {
          short8 bhi;
          if (LAYER==0) bhi = *(const short8*)&Bx[((kq*3+nt)*KTX + kt)*512 + lane*8];
          else          bhi = *(const short8*)&wxhi_b[(nt*KTX + kt)*512];
          short8 blo =    *(const short8*)&wxlo_b[(nt*KTX + kt)*512];
          xacc[nt] = MFMA(ahi, bhi, xacc[nt]);
          xacc[nt] = MFMA(alo, bhi, xacc[nt]);
          xacc[nt] = MFMA(ahi, blo, xacc[nt]);
        }
      }
    }
    { // recurrent: h (32 x 1024) @ Wh slice, h via LLC-coherent loads
      const u32* hrow = hbuf + cur*32768 + arow*1024 + kq*256 + kseg;
#pragma unroll 4
      for (int kt = 0; kt < 8; ++kt) {
        const u64* hq = (const u64*)(hrow + kt*32);
        u64 q0 = __hip_atomic_load(hq+0, __ATOMIC_RELAXED, __HIP_MEMORY_SCOPE_AGENT);
        u64 q1 = __hip_atomic_load(hq+1, __ATOMIC_RELAXED, __HIP_MEMORY_SCOPE_AGENT);
        u64 q2 = __hip_atomic_load(hq+2, __ATOMIC_RELAXED, __HIP_MEMORY_SCOPE_AGENT);
        u64 q3 = __hip_atomic_load(hq+3, __ATOMIC_RELAXED, __HIP_MEMORY_SCOPE_AGENT);
        short8 ahi, alo; unpackq(q0,q1,q2,q3, ahi, alo);
#pragma unroll
        for (int nt = 0; nt < 3; ++nt) {
          short8 bhi = *(const short8*)&Brec[((kq*3+nt)*8 + kt)*512 + lane*8];
          short8 blo = *(const short8*)&whlo_b[(nt*8 + kt)*512];
          racc[nt] = MFMA(ahi, bhi, racc[nt]);
          racc[nt] = MFMA(alo, bhi, racc[nt]);
          racc[nt] = MFMA(ahi, blo, racc[nt]);
        }
      }
    }
    { // write gate pre-activations to LDS (D layout: row=(lane>>4)*4+r, col=lane&15)
      const int colu = lane & 15;
      const int rb4 = 16*m + ((lane >> 4) << 2);
#pragma unroll
      for (int rgi = 0; rgi < 4; ++rgi) {
        const int bb = rb4 + rgi;
        exch[((kq*4 + 0)*32 + bb)*16 + colu] = racc[0][rgi] + xacc[0][rgi];
        exch[((kq*4 + 1)*32 + bb)*16 + colu] = racc[1][rgi] + xacc[1][rgi];
        exch[((kq*4 + 2)*32 + bb)*16 + colu] = xacc[2][rgi];
        exch[((kq*4 + 3)*32 + bb)*16 + colu] = racc[2][rgi];
      }
    }
    __syncthreads();
    { // elementwise gates; one (b, unit) per thread
      float sz=0.f, sr=0.f, shx=0.f, shr=0.f;
#pragma unroll
      for (int k4 = 0; k4 < 4; ++k4) {
        const float* e = &exch[((k4*4)*32 + eb)*16 + eul];
        sz  += e[0];
        sr  += e[512];
        shx += e[1024];
        shr += e[1536];
      }
      float z = 1.f/(1.f + __expf(-(sz + zb)));
      float r = 1.f/(1.f + __expf(-(sr + rb)));
      float pre = shx + hxb + r*(shr + hrb);
      float ex = __expf(-2.f*fabsf(pre));
      float th = (1.f - ex)/(1.f + ex);
      float hh = copysignf(th, pre);
      float ho = harr[tid];
      float hn = z*ho + (1.f - z)*hh;
      harr[tid] = hn;
      u32 pk = pack_f(hn);
      __hip_atomic_store(hbuf + nxt*32768 + eb*1024 + u0 + eul, pk,
                         __ATOMIC_RELAXED, __HIP_MEMORY_SCOPE_AGENT);
      if (LAYER==0) {
        if ((t & 3) == 0)
          out_pack[((size_t)(t>>2)*32 + eb)*1024 + u0 + eul] = pk;
      } else {
        out_pack[((size_t)t*32 + eb)*1024 + u0 + eul] = pk;
      }
    }
    asm volatile("s_waitcnt vmcnt(0)" ::: "memory");
    __syncthreads();
    if (tid == 0)
      __hip_atomic_store(flags + wg, t+1, __ATOMIC_RELAXED, __HIP_MEMORY_SCOPE_AGENT);
    if (t + 1 < T) {
      int fv;
      do { fv = __hip_atomic_load(flags + lane, __ATOMIC_RELAXED, __HIP_MEMORY_SCOPE_AGENT); }
      while (__all(fv >= (t+1)) == 0);
    }
    cur = nxt;
  }
}

// ---------------- final dense head ----------------
// h2 [250][32][1024] packed ; W [1024][41] ; out [32][250][41] f32
__global__ __launch_bounds__(256, 1)
void dense_k(const u32* __restrict__ h2, const float* __restrict__ W,
             const float* __restrict__ bias, float* __restrict__ out){
  __shared__ float rows[32*1025];
  const int ts = blockIdx.x;
  const u32* src = h2 + (size_t)ts*32768;
  for (int i = threadIdx.x; i < 32768; i += 256){
    u32 p = src[i];
    rows[(i>>10)*1025 + (i&1023)] = bf2f(p & 0xffffu) + bf2f(p >> 16);
  }
  __syncthreads();
  const int b = threadIdx.x >> 3, cg = threadIdx.x & 7;
  float acc[6] = {0.f,0.f,0.f,0.f,0.f,0.f};
  for (int k = 0; k < 1024; ++k){
    float hv = rows[b*1025 + k];
    const float* wr = W + k*41;
#pragma unroll
    for (int j = 0; j < 6; ++j){ int c = cg + 8*j; if (c < 41) acc[j] += hv*wr[c]; }
  }
#pragma unroll
  for (int j = 0; j < 6; ++j){
    int c = cg + 8*j;
    if (c < 41) out[((size_t)b*250 + ts)*41 + c] = acc[j] + bias[c];
  }
}

// ---------------- launch ----------------
extern "C" void kernel_launch(void* const* d_in, const int* in_sizes, int n_in,
                              void* d_out, int out_size, void* d_ws, size_t ws_size,
                              hipStream_t stream) {
  const float* x      = (const float*)d_in[0];
  const float* conv_w = (const float*)d_in[1];
  const float* h0i    = (const float*)d_in[2];
  const float* w0x    = (const float*)d_in[3];
  const float* w0h    = (const float*)d_in[4];
  const float* b0     = (const float*)d_in[5];
  const float* w1x    = (const float*)d_in[6];
  const float* w1h    = (const float*)d_in[7];
  const float* b1     = (const float*)d_in[8];
  const float* dw     = (const float*)d_in[9];
  const float* db     = (const float*)d_in[10];
  float* outp = (float*)d_out;

  if (ws_size < WS_NEED) return;  // workspace too small: leave output poisoned (visible failure)

  char* ws = (char*)d_ws;
  u32* y_pack   = (u32*)(ws + OFF_Y);
  u32* out2     = (u32*)(ws + OFF_Y);      // reuse after y_pack is dead
  u32* sub_pack = (u32*)(ws + OFF_SUB);
  u16* w0x_hi = (u16*)(ws + OFF_W0XH); u16* w0x_lo = (u16*)(ws + OFF_W0XL);
  u16* w0h_hi = (u16*)(ws + OFF_W0HH); u16* w0h_lo = (u16*)(ws + OFF_W0HL);
  u16* w1x_hi = (u16*)(ws + OFF_W1XH); u16* w1x_lo = (u16*)(ws + OFF_W1XL);
  u16* w1h_hi = (u16*)(ws + OFF_W1HH); u16* w1h_lo = (u16*)(ws + OFF_W1HL);
  u32* hb0 = (u32*)(ws + OFF_HB0);
  u32* hb1 = (u32*)(ws + OFF_HB1);
  int* fl0 = (int*)(ws + OFF_FL0);
  int* fl1 = (int*)(ws + OFF_FL1);

  init_state<<<64, 512, 0, stream>>>(h0i, hb0, hb1, fl0, fl1);
  build_frags<<<1024, 256, 0, stream>>>(w0x, w0x_hi, w0x_lo, 256);
  build_frags<<<1024, 256, 0, stream>>>(w0h, w0h_hi, w0h_lo, 1024);
  build_frags<<<1024, 256, 0, stream>>>(w1x, w1x_hi, w1x_lo, 1024);
  build_frags<<<1024, 256, 0, stream>>>(w1h, w1h_hi, w1h_lo, 1024);
  conv_pack<<<4096, 256, 0, stream>>>(x, conv_w, y_pack);

  gru_persist<0><<<64, 512, 0, stream>>>(y_pack, w0x_hi, w0x_lo, w0h_hi, w0h_lo,
                                         b0, hb0, fl0, sub_pack);
  gru_persist<1><<<64, 512, 0, stream>>>(sub_pack, w1x_hi, w1x_lo, w1h_hi, w1h_lo,
                                         b1, hb1, fl1, out2);

  dense_k<<<250, 256, 0, stream>>>(out2, dw, db, outp);
}

// Round 2
// 15870.689 us; speedup vs baseline: 1.1346x; 1.1346x over previous
//
#include <hip/hip_runtime.h>

typedef unsigned int u32;
typedef unsigned long long u64;
typedef unsigned short u16;
typedef __attribute__((ext_vector_type(8))) short short8;
typedef __attribute__((ext_vector_type(4))) float f32x4;

#define MFMA(a,b,c) __builtin_amdgcn_mfma_f32_16x16x32_bf16((a),(b),(c),0,0,0)

__device__ __forceinline__ float bf2f(u32 b){ union{u32 u; float f;} v; v.u = b<<16; return v.f; }
__device__ __forceinline__ u16 f2bf(float f){ union{float f; u32 u;} v; v.f = f; u32 u = v.u;
  return (u16)((u + 0x7fffu + ((u>>16)&1u)) >> 16); }
__device__ __forceinline__ u32 pack_f(float v){
  u16 hi = f2bf(v); u16 lo = f2bf(v - bf2f(hi)); return (u32)hi | ((u32)lo<<16); }

__device__ __forceinline__ void unpack8(uint4 a, uint4 b, short8& hi, short8& lo){
  u32 w[8] = {a.x,a.y,a.z,a.w,b.x,b.y,b.z,b.w};
#pragma unroll
  for (int j=0;j<8;++j){ hi[j] = (short)(w[j] & 0xffffu); lo[j] = (short)(w[j] >> 16); }
}
__device__ __forceinline__ void unpackq(u64 q0,u64 q1,u64 q2,u64 q3, short8& hi, short8& lo){
  u32 w[8] = {(u32)q0,(u32)(q0>>32),(u32)q1,(u32)(q1>>32),(u32)q2,(u32)(q2>>32),(u32)q3,(u32)(q3>>32)};
#pragma unroll
  for (int j=0;j<8;++j){ hi[j] = (short)(w[j] & 0xffffu); lo[j] = (short)(w[j] >> 16); }
}

// ---------------- workspace layout (bytes) ----------------
constexpr size_t OFF_Y    = 0;            // u32[1000][32][256] = 32,768,000 ; reused as out2 [250][32][1024]
constexpr size_t OFF_SUB  = 32768000;     // u32[250][32][1024] = 32,768,000
constexpr size_t OFF_W0XH = 65536000;     // u16[256*3072]  frag layout
constexpr size_t OFF_W0XL = 67108864;
constexpr size_t OFF_W0HH = 68681728;     // u16[1024*3072] frag layout
constexpr size_t OFF_W0HL = 74973184;
constexpr size_t OFF_W1XH = 81264640;
constexpr size_t OFF_W1XL = 87556096;
constexpr size_t OFF_W1HH = 93847552;
constexpr size_t OFF_W1HL = 100139008;
constexpr size_t OFF_HB0  = 106430464;    // u32[3][32][1024]
constexpr size_t OFF_HB1  = 106823680;
constexpr size_t OFF_FL0  = 107216896;    // int[64] (padded 1KB)
constexpr size_t OFF_FL1  = 107217920;
constexpr size_t WS_NEED  = 107218944;

// ---------------- weight fragment builder ----------------
// layout: [wg=64][kq=4][nt=3][kt=K/128][lane=64][8]
// element: k = kq*(K/4) + kt*32 + (lane>>4)*8 + j ; col = nt*1024 + wg*16 + (lane&15)
__global__ void build_frags(const float* __restrict__ W, u16* __restrict__ fhi,
                            u16* __restrict__ flo, int K){
  const int KT = K >> 7;
  const int KQ4 = K >> 2;
  size_t total = (size_t)K * 3072;
  for (size_t i = (size_t)blockIdx.x*blockDim.x + threadIdx.x; i < total;
       i += (size_t)gridDim.x*blockDim.x){
    int j = (int)(i & 7); size_t r = i >> 3;
    int l = (int)(r & 63); r >>= 6;
    int kt = (int)(r % KT); r /= KT;
    int nt = (int)(r % 3); r /= 3;
    int kq = (int)(r & 3); r >>= 2;
    int wg = (int)r;
    int k = kq*KQ4 + kt*32 + ((l>>4)<<3) + j;
    int col = nt*1024 + wg*16 + (l&15);
    float v = W[(size_t)k*3072 + col];
    u16 hi = f2bf(v);
    u16 lo = f2bf(v - bf2f(hi));
    fhi[i] = hi; flo[i] = lo;
  }
}

// ---------------- init h0 + flags ----------------
__global__ void init_state(const float* __restrict__ h0, u32* hb0, u32* hb1,
                           int* f0, int* f1){
  int i = blockIdx.x*blockDim.x + threadIdx.x;
  if (i < 64){ f0[i]=0; f1[i]=0; }
  if (i < 32768){
    int uu = i & 1023;
    hb0[i] = pack_f(h0[uu]);
    hb1[i] = 0u;
  }
}

// ---------------- conv + relu + pack ----------------
// x [32][1000][256] f32 -> yp [1000][32][256] packed {bf16hi, bf16lo}
__global__ void conv_pack(const float* __restrict__ x, const float* __restrict__ cw,
                          u32* __restrict__ yp){
  for (size_t i = (size_t)blockIdx.x*blockDim.x + threadIdx.x; i < 8192000ull;
       i += (size_t)gridDim.x*blockDim.x){
    int f = (int)(i & 255); int b = (int)((i>>8)&31); int t = (int)(i>>13);
    const float* xb = x + ((size_t)b*1000 + t)*256 + f;
    float acc = xb[0]*cw[256+f];
    if (t > 0)   acc += xb[-256]*cw[f];
    if (t < 999) acc += xb[256]*cw[512+f];
    acc = fmaxf(acc, 0.0f);
    yp[i] = pack_f(acc);
  }
}

// ---------------- persistent GRU layer ----------------
// 64 WGs x 512 threads (8 waves). WG owns 16 units (48 gate cols).
// wave role: m = wave&1 (batch tile), kq = wave>>1 (K quarter).
// Step order: xproj (h-independent) FIRST, then wave0-only flag poll,
// then recurrent matmul -> gates -> h store -> flag publish.
template<int LAYER>
__global__ __launch_bounds__(512, 1)
void gru_persist(const u32* __restrict__ xin,
                 const u16* __restrict__ wx_hi, const u16* __restrict__ wx_lo,
                 const u16* __restrict__ wh_hi, const u16* __restrict__ wh_lo,
                 const float* __restrict__ bias,
                 u32* hbuf, int* flags, u32* out_pack)
{
  constexpr int T   = (LAYER==0) ? 1000 : 250;
  constexpr int KX  = (LAYER==0) ? 256 : 1024;
  constexpr int KTX = KX >> 7;           // ktiles per quarter: 2 or 8
  __shared__ u16 Brec[4*3*8*512];                       // 96KB: Wh-hi slice
  __shared__ u16 Bx[(LAYER==0) ? (4*3*2*512) : 8];      // 24KB layer0 Wx-hi slice
  __shared__ float exch[4*4*32*16];                     // 32KB gate exchange
  __shared__ float harr[512];                           // own h (fp32)

  const int tid  = threadIdx.x;
  const int wg   = blockIdx.x;
  const int lane = tid & 63;
  const int wave = tid >> 6;
  const int m    = wave & 1;
  const int kq   = wave >> 1;
  const int u0   = wg * 16;

  { // stage Whi (and layer0 Wx-hi) into LDS
    const uint4* s = (const uint4*)(wh_hi + (size_t)wg*(4*3*8*512));
    uint4* d = (uint4*)Brec;
    for (int i = tid; i < (4*3*8*512)/8; i += 512) d[i] = s[i];
    if (LAYER==0){
      const uint4* s2 = (const uint4*)(wx_hi + (size_t)wg*(4*3*KTX*512));
      uint4* d2 = (uint4*)Bx;
      for (int i = tid; i < (4*3*KTX*512)/8; i += 512) d2[i] = s2[i];
    }
    u32 p = hbuf[(tid>>4)*1024 + u0 + (tid&15)];
    harr[tid] = bf2f(p & 0xffffu) + bf2f(p >> 16);
  }
  __syncthreads();

  // elementwise-role constants
  const int eb = tid >> 4, eul = tid & 15, eu = u0 + eul;
  const float zb  = bias[eu]        + bias[3072 + eu];
  const float rb  = bias[1024 + eu] + bias[4096 + eu];
  const float hxb = bias[2048 + eu];
  const float hrb = bias[5120 + eu];

  // wave-role constants
  const int arow = 16*m + (lane & 15);
  const int kseg = (lane >> 4) << 3;
  const u16* wxhi_b = wx_hi + ((size_t)(wg*4 + kq)*3*KTX)*512 + lane*8;
  const u16* wxlo_b = wx_lo + ((size_t)(wg*4 + kq)*3*KTX)*512 + lane*8;
  const u16* whlo_b = wh_lo + ((size_t)(wg*4 + kq)*3*8)*512 + lane*8;

  for (int t = 0; t < T; ++t) {
    const int cur = t % 3;
    const int nxt = (t+1) % 3;
    f32x4 xacc[3], racc[3];
#pragma unroll
    for (int nt=0; nt<3; ++nt){
      xacc[nt] = (f32x4){0.f,0.f,0.f,0.f};
      racc[nt] = (f32x4){0.f,0.f,0.f,0.f};
    }
    { // fused xproj: xin[t] (32 x KX) @ Wx slice — independent of h_t.
      // Runs BEFORE the flag poll so it hides laggard-WG flag propagation.
      const u32* xrow = xin + ((size_t)t*32 + arow)*KX + kq*(KX>>2) + kseg;
#pragma unroll 2
      for (int kt = 0; kt < KTX; ++kt) {
        uint4 a0 = *(const uint4*)(xrow + kt*32);
        uint4 a1 = *(const uint4*)(xrow + kt*32 + 4);
        short8 ahi, alo; unpack8(a0, a1, ahi, alo);
#pragma unroll
        for (int nt = 0; nt < 3; ++nt) {
          short8 bhi;
          if (LAYER==0) bhi = *(const short8*)&Bx[((kq*3+nt)*KTX + kt)*512 + lane*8];
          else          bhi = *(const short8*)&wxhi_b[(nt*KTX + kt)*512];
          short8 blo =    *(const short8*)&wxlo_b[(nt*KTX + kt)*512];
          xacc[nt] = MFMA(ahi, bhi, xacc[nt]);
          xacc[nt] = MFMA(alo, bhi, xacc[nt]);
          xacc[nt] = MFMA(ahi, blo, xacc[nt]);
        }
      }
    }
    // wait for h_t: ONE wave polls (avoids LLC/fabric congestion collapse
    // from 32K lanes hammering bypass loads); others park at the barrier.
    if (t > 0) {
      if (wave == 0) {
        int fv;
        do { fv = __hip_atomic_load(flags + lane, __ATOMIC_RELAXED, __HIP_MEMORY_SCOPE_AGENT); }
        while (__all(fv >= t) == 0);
      }
      __syncthreads();
    }
    { // recurrent: h (32 x 1024) @ Wh slice, h via LLC-coherent loads
      const u32* hrow = hbuf + cur*32768 + arow*1024 + kq*256 + kseg;
#pragma unroll 4
      for (int kt = 0; kt < 8; ++kt) {
        const u64* hq = (const u64*)(hrow + kt*32);
        u64 q0 = __hip_atomic_load(hq+0, __ATOMIC_RELAXED, __HIP_MEMORY_SCOPE_AGENT);
        u64 q1 = __hip_atomic_load(hq+1, __ATOMIC_RELAXED, __HIP_MEMORY_SCOPE_AGENT);
        u64 q2 = __hip_atomic_load(hq+2, __ATOMIC_RELAXED, __HIP_MEMORY_SCOPE_AGENT);
        u64 q3 = __hip_atomic_load(hq+3, __ATOMIC_RELAXED, __HIP_MEMORY_SCOPE_AGENT);
        short8 ahi, alo; unpackq(q0,q1,q2,q3, ahi, alo);
#pragma unroll
        for (int nt = 0; nt < 3; ++nt) {
          short8 bhi = *(const short8*)&Brec[((kq*3+nt)*8 + kt)*512 + lane*8];
          short8 blo = *(const short8*)&whlo_b[(nt*8 + kt)*512];
          racc[nt] = MFMA(ahi, bhi, racc[nt]);
          racc[nt] = MFMA(alo, bhi, racc[nt]);
          racc[nt] = MFMA(ahi, blo, racc[nt]);
        }
      }
    }
    { // write gate pre-activations to LDS (D layout: row=(lane>>4)*4+r, col=lane&15)
      const int colu = lane & 15;
      const int rb4 = 16*m + ((lane >> 4) << 2);
#pragma unroll
      for (int rgi = 0; rgi < 4; ++rgi) {
        const int bb = rb4 + rgi;
        exch[((kq*4 + 0)*32 + bb)*16 + colu] = racc[0][rgi] + xacc[0][rgi];
        exch[((kq*4 + 1)*32 + bb)*16 + colu] = racc[1][rgi] + xacc[1][rgi];
        exch[((kq*4 + 2)*32 + bb)*16 + colu] = xacc[2][rgi];
        exch[((kq*4 + 3)*32 + bb)*16 + colu] = racc[2][rgi];
      }
    }
    __syncthreads();
    { // elementwise gates; one (b, unit) per thread
      float sz=0.f, sr=0.f, shx=0.f, shr=0.f;
#pragma unroll
      for (int k4 = 0; k4 < 4; ++k4) {
        const float* e = &exch[((k4*4)*32 + eb)*16 + eul];
        sz  += e[0];
        sr  += e[512];
        shx += e[1024];
        shr += e[1536];
      }
      float z = 1.f/(1.f + __expf(-(sz + zb)));
      float r = 1.f/(1.f + __expf(-(sr + rb)));
      float pre = shx + hxb + r*(shr + hrb);
      float ex = __expf(-2.f*fabsf(pre));
      float th = (1.f - ex)/(1.f + ex);
      float hh = copysignf(th, pre);
      float ho = harr[tid];
      float hn = z*ho + (1.f - z)*hh;
      harr[tid] = hn;
      u32 pk = pack_f(hn);
      __hip_atomic_store(hbuf + nxt*32768 + eb*1024 + u0 + eul, pk,
                         __ATOMIC_RELAXED, __HIP_MEMORY_SCOPE_AGENT);
      if (LAYER==0) {
        if ((t & 3) == 0)
          out_pack[((size_t)(t>>2)*32 + eb)*1024 + u0 + eul] = pk;
      } else {
        out_pack[((size_t)t*32 + eb)*1024 + u0 + eul] = pk;
      }
    }
    asm volatile("s_waitcnt vmcnt(0)" ::: "memory");
    __syncthreads();
    if (tid == 0)
      __hip_atomic_store(flags + wg, t+1, __ATOMIC_RELAXED, __HIP_MEMORY_SCOPE_AGENT);
  }
}

// ---------------- final dense head ----------------
// h2 [250][32][1024] packed ; W [1024][41] ; out [32][250][41] f32
__global__ __launch_bounds__(256, 1)
void dense_k(const u32* __restrict__ h2, const float* __restrict__ W,
             const float* __restrict__ bias, float* __restrict__ out){
  __shared__ float rows[32*1025];
  const int ts = blockIdx.x;
  const u32* src = h2 + (size_t)ts*32768;
  for (int i = threadIdx.x; i < 32768; i += 256){
    u32 p = src[i];
    rows[(i>>10)*1025 + (i&1023)] = bf2f(p & 0xffffu) + bf2f(p >> 16);
  }
  __syncthreads();
  const int b = threadIdx.x >> 3, cg = threadIdx.x & 7;
  float acc[6] = {0.f,0.f,0.f,0.f,0.f,0.f};
  for (int k = 0; k < 1024; ++k){
    float hv = rows[b*1025 + k];
    const float* wr = W + k*41;
#pragma unroll
    for (int j = 0; j < 6; ++j){ int c = cg + 8*j; if (c < 41) acc[j] += hv*wr[c]; }
  }
#pragma unroll
  for (int j = 0; j < 6; ++j){
    int c = cg + 8*j;
    if (c < 41) out[((size_t)b*250 + ts)*41 + c] = acc[j] + bias[c];
  }
}

// ---------------- launch ----------------
extern "C" void kernel_launch(void* const* d_in, const int* in_sizes, int n_in,
                              void* d_out, int out_size, void* d_ws, size_t ws_size,
                              hipStream_t stream) {
  const float* x      = (const float*)d_in[0];
  const float* conv_w = (const float*)d_in[1];
  const float* h0i    = (const float*)d_in[2];
  const float* w0x    = (const float*)d_in[3];
  const float* w0h    = (const float*)d_in[4];
  const float* b0     = (const float*)d_in[5];
  const float* w1x    = (const float*)d_in[6];
  const float* w1h    = (const float*)d_in[7];
  const float* b1     = (const float*)d_in[8];
  const float* dw     = (const float*)d_in[9];
  const float* db     = (const float*)d_in[10];
  float* outp = (float*)d_out;

  if (ws_size < WS_NEED) return;  // workspace too small: leave output poisoned (visible failure)

  char* ws = (char*)d_ws;
  u32* y_pack   = (u32*)(ws + OFF_Y);
  u32* out2     = (u32*)(ws + OFF_Y);      // reuse after y_pack is dead
  u32* sub_pack = (u32*)(ws + OFF_SUB);
  u16* w0x_hi = (u16*)(ws + OFF_W0XH); u16* w0x_lo = (u16*)(ws + OFF_W0XL);
  u16* w0h_hi = (u16*)(ws + OFF_W0HH); u16* w0h_lo = (u16*)(ws + OFF_W0HL);
  u16* w1x_hi = (u16*)(ws + OFF_W1XH); u16* w1x_lo = (u16*)(ws + OFF_W1XL);
  u16* w1h_hi = (u16*)(ws + OFF_W1HH); u16* w1h_lo = (u16*)(ws + OFF_W1HL);
  u32* hb0 = (u32*)(ws + OFF_HB0);
  u32* hb1 = (u32*)(ws + OFF_HB1);
  int* fl0 = (int*)(ws + OFF_FL0);
  int* fl1 = (int*)(ws + OFF_FL1);

  init_state<<<64, 512, 0, stream>>>(h0i, hb0, hb1, fl0, fl1);
  build_frags<<<1024, 256, 0, stream>>>(w0x, w0x_hi, w0x_lo, 256);
  build_frags<<<1024, 256, 0, stream>>>(w0h, w0h_hi, w0h_lo, 1024);
  build_frags<<<1024, 256, 0, stream>>>(w1x, w1x_hi, w1x_lo, 1024);
  build_frags<<<1024, 256, 0, stream>>>(w1h, w1h_hi, w1h_lo, 1024);
  conv_pack<<<4096, 256, 0, stream>>>(x, conv_w, y_pack);

  gru_persist<0><<<64, 512, 0, stream>>>(y_pack, w0x_hi, w0x_lo, w0h_hi, w0h_lo,
                                         b0, hb0, fl0, sub_pack);
  gru_persist<1><<<64, 512, 0, stream>>>(sub_pack, w1x_hi, w1x_lo, w1h_hi, w1h_lo,
                                         b1, hb1, fl1, out2);

  dense_k<<<250, 256, 0, stream>>>(out2, dw, db, outp);
}

// Round 3
// 12876.517 us; speedup vs baseline: 1.3984x; 1.2325x over previous
//
#include <hip/hip_runtime.h>

typedef unsigned int u32;
typedef unsigned long long u64;
typedef unsigned short u16;
typedef __attribute__((ext_vector_type(8))) short short8;
typedef __attribute__((ext_vector_type(4))) float f32x4;

#define MFMA(a,b,c) __builtin_amdgcn_mfma_f32_16x16x32_bf16((a),(b),(c),0,0,0)
#define ALOAD64(p)    __hip_atomic_load((p), __ATOMIC_RELAXED, __HIP_MEMORY_SCOPE_AGENT)
#define ALOAD32(p)    __hip_atomic_load((p), __ATOMIC_RELAXED, __HIP_MEMORY_SCOPE_AGENT)
#define ASTORE32(p,v) __hip_atomic_store((p),(v), __ATOMIC_RELAXED, __HIP_MEMORY_SCOPE_AGENT)

__device__ __forceinline__ float bf2f(u32 b){ union{u32 u; float f;} v; v.u = b<<16; return v.f; }
__device__ __forceinline__ u16 f2bf(float f){ union{float f; u32 u;} v; v.f = f; u32 u = v.u;
  return (u16)((u + 0x7fffu + ((u>>16)&1u)) >> 16); }
__device__ __forceinline__ u32 pack_f(float v){
  u16 hi = f2bf(v); u16 lo = f2bf(v - bf2f(hi)); return (u32)hi | ((u32)lo<<16); }

__device__ __forceinline__ void unpack8(uint4 a, uint4 b, short8& hi, short8& lo){
  u32 w[8] = {a.x,a.y,a.z,a.w,b.x,b.y,b.z,b.w};
#pragma unroll
  for (int j=0;j<8;++j){ hi[j] = (short)(w[j] & 0xffffu); lo[j] = (short)(w[j] >> 16); }
}
__device__ __forceinline__ void unpackq(u64 q0,u64 q1,u64 q2,u64 q3, short8& hi, short8& lo){
  u32 w[8] = {(u32)q0,(u32)(q0>>32),(u32)q1,(u32)(q1>>32),(u32)q2,(u32)(q2>>32),(u32)q3,(u32)(q3>>32)};
#pragma unroll
  for (int j=0;j<8;++j){ hi[j] = (short)(w[j] & 0xffffu); lo[j] = (short)(w[j] >> 16); }
}

// ---------------- workspace layout (bytes) ----------------
// Weight blobs are col-COMPACT: 12 real gate-cols per WG (zeros synthesized in LDS).
// blob order: [wg=256][kq=8][kt=K/256][kseg=4][c=12][j=8] u16
constexpr size_t OFF_Y    = 0;            // u32[1000][32][256]; reused as out2 [250][32][1024]
constexpr size_t OFF_SUB  = 32768000;     // u32[250][32][1024]
constexpr size_t OFF_W0XH = 65536000;     // K=256 : 786,432 u16 = 1,572,864 B
constexpr size_t OFF_W0XL = 67108864;
constexpr size_t OFF_W0HH = 68681728;     // K=1024: 3,145,728 u16 = 6,291,456 B
constexpr size_t OFF_W0HL = 74973184;
constexpr size_t OFF_W1XH = 81264640;
constexpr size_t OFF_W1XL = 87556096;
constexpr size_t OFF_W1HH = 93847552;
constexpr size_t OFF_W1HL = 100139008;
constexpr size_t OFF_HB0  = 106430464;    // u32[2][32][1024] = 262,144 B
constexpr size_t OFF_HB1  = 106692608;
constexpr size_t OFF_FL0  = 106954752;    // int[256] padded 1KB
constexpr size_t OFF_FL1  = 106955776;
constexpr size_t WS_NEED  = 106956800;

// ---------------- weight fragment builder (compact 12-col) ----------------
// element i -> j=i&7; c=(i>>3)%12; kseg; kt; kq; wg
// k = kq*(K/8) + kt*32 + kseg*8 + j ; col = (c>>2)*1024 + wg*4 + (c&3)
__global__ void build_frags(const float* __restrict__ W, u16* __restrict__ fhi,
                            u16* __restrict__ flo, int K){
  const int KT = K >> 8;                  // kt per kq (K/256)
  size_t total = (size_t)K * 12 * 256;
  for (size_t i = (size_t)blockIdx.x*blockDim.x + threadIdx.x; i < total;
       i += (size_t)gridDim.x*blockDim.x){
    int j = (int)(i & 7); size_t r = i >> 3;
    int c = (int)(r % 12); r /= 12;
    int kseg = (int)(r & 3); r >>= 2;
    int kt = (int)(r % KT); r /= KT;
    int kq = (int)(r & 7); r >>= 3;
    int wg = (int)r;
    int k = kq*(K>>3) + kt*32 + kseg*8 + j;
    int col = (c>>2)*1024 + wg*4 + (c&3);
    float v = W[(size_t)k*3072 + col];
    u16 hi = f2bf(v);
    u16 lo = f2bf(v - bf2f(hi));
    fhi[i] = hi; flo[i] = lo;
  }
}

// ---------------- init h0 + flags ----------------
__global__ void init_state(const float* __restrict__ h0, u32* hb0, u32* hb1,
                           int* f0, int* f1){
  int i = blockIdx.x*blockDim.x + threadIdx.x;
  if (i < 256){ f0[i]=0; f1[i]=0; }
  if (i < 32768){
    int uu = i & 1023;
    hb0[i] = pack_f(h0[uu]);   // slot 0
    hb1[i] = 0u;               // slot 0
  }
}

// ---------------- conv + relu + pack ----------------
// x [32][1000][256] f32 -> yp [1000][32][256] packed {bf16hi, bf16lo}
__global__ void conv_pack(const float* __restrict__ x, const float* __restrict__ cw,
                          u32* __restrict__ yp){
  for (size_t i = (size_t)blockIdx.x*blockDim.x + threadIdx.x; i < 8192000ull;
       i += (size_t)gridDim.x*blockDim.x){
    int f = (int)(i & 255); int b = (int)((i>>8)&31); int t = (int)(i>>13);
    const float* xb = x + ((size_t)b*1000 + t)*256 + f;
    float acc = xb[0]*cw[256+f];
    if (t > 0)   acc += xb[-256]*cw[f];
    if (t < 999) acc += xb[256]*cw[512+f];
    acc = fmaxf(acc, 0.0f);
    yp[i] = pack_f(acc);
  }
}

// ---------------- persistent GRU layer ----------------
// 256 WGs x 1024 threads (16 waves, 4/SIMD). WG owns 4 units.
// Wave role: m = wave&1 (16-row batch half), kq = wave>>1 (K eighth).
// Fused 16-col MFMA tile: xproj weights [z4|r4|h4|0], recurrent [z4|r4|0|h4]
// so xacc+racc = {zpre partial, rpre partial, xh, rh} directly.
// ALL weights (hi+lo) LDS-resident; only h + xin streamed per step.
template<int LAYER>
__global__ __launch_bounds__(1024, 1)
void gru_persist(const u32* __restrict__ xin,
                 const u16* __restrict__ wxf_hi, const u16* __restrict__ wxf_lo,
                 const u16* __restrict__ whf_hi, const u16* __restrict__ whf_lo,
                 const float* __restrict__ bias,
                 u32* hbuf, int* flags, u32* out_pack)
{
  constexpr int T   = (LAYER==0) ? 1000 : 250;
  constexpr int KX  = (LAYER==0) ? 256 : 1024;
  constexpr int KTX = KX >> 8;           // kt per kq for Wx: 1 or 4
  constexpr int KTH = 4;                 // kt per kq for Wh (K=1024)
  __shared__ u16 WxHi[8*KTX*512], WxLo[8*KTX*512];   // L0: 8KB ea, L1: 32KB ea
  __shared__ u16 WhHi[8*KTH*512], WhLo[8*KTH*512];   // 32KB ea
  __shared__ float exch[8*32*18];                    // 18KB, stride-18 (<=2-way conflicts)
  __shared__ float harr[128];                        // own h fp32

  const int tid  = threadIdx.x;
  const int wg   = blockIdx.x;
  const int lane = tid & 63;
  const int wave = tid >> 6;
  const int m    = wave & 1;
  const int kq   = wave >> 1;
  const int u0   = wg * 4;
  const int lo16 = lane & 15, hi16 = lane >> 4;
  const int lane_off = hi16*128 + lo16*8;           // B-frag LDS elem offset

  { // zero weight LDS (provides the pad-zero cols)
    for (int i = tid; i < 8*KTX*512/4; i += 1024){ ((u64*)WxHi)[i]=0; ((u64*)WxLo)[i]=0; }
    for (int i = tid; i < 8*KTH*512/4; i += 1024){ ((u64*)WhHi)[i]=0; ((u64*)WhLo)[i]=0; }
  }
  __syncthreads();
  { // scatter compact blobs into padded LDS tiles
    const u16* bx_hi = wxf_hi + (size_t)wg*KX*12;
    const u16* bx_lo = wxf_lo + (size_t)wg*KX*12;
    const u16* bh_hi = whf_hi + (size_t)wg*1024*12;
    const u16* bh_lo = whf_lo + (size_t)wg*1024*12;
    for (int i = tid; i < 8*KTX*48; i += 1024){
      int c = i % 12; int r = i/12; int kseg = r & 3; r >>= 2;
      int kt = r % KTX; int kqq = r / KTX;
      int ldsoff = ((kqq*KTX+kt)*4+kseg)*128 + c*8;            // xproj: c -> c
      *(short8*)&WxHi[ldsoff] = *(const short8*)&bx_hi[(size_t)i*8];
      *(short8*)&WxLo[ldsoff] = *(const short8*)&bx_lo[(size_t)i*8];
    }
    for (int i = tid; i < 8*KTH*48; i += 1024){
      int c = i % 12; int r = i/12; int kseg = r & 3; r >>= 2;
      int kt = r % KTH; int kqq = r / KTH;
      int cm = (c < 8) ? c : (c + 4);                          // rec: h-cols -> 12..15
      int ldsoff = ((kqq*KTH+kt)*4+kseg)*128 + cm*8;
      *(short8*)&WhHi[ldsoff] = *(const short8*)&bh_hi[(size_t)i*8];
      *(short8*)&WhLo[ldsoff] = *(const short8*)&bh_lo[(size_t)i*8];
    }
    if (tid < 128){
      u32 p = hbuf[(tid>>2)*1024 + u0 + (tid&3)];              // slot 0
      harr[tid] = bf2f(p & 0xffffu) + bf2f(p >> 16);
    }
  }
  __syncthreads();

  // elementwise-role constants (valid where tid<128; in-bounds everywhere)
  const int eb = tid >> 2, eu_l = tid & 3, eu = u0 + eu_l;
  const float zb  = bias[eu]        + bias[3072 + eu];
  const float rbv = bias[1024 + eu] + bias[4096 + eu];
  const float hxb = bias[2048 + eu];
  const float hrb = bias[5120 + eu];

  for (int t = 0; t < T; ++t) {
    const int cur = t & 1, nxt = cur ^ 1;
    f32x4 xacc = (f32x4){0.f,0.f,0.f,0.f};
    f32x4 racc = (f32x4){0.f,0.f,0.f,0.f};
    { // xproj (h-independent; overlaps laggard flag propagation)
      const u32* xrow = xin + ((size_t)t*32 + 16*m + lo16)*KX + kq*(KX>>3) + hi16*8;
#pragma unroll
      for (int kt = 0; kt < KTX; ++kt) {
        uint4 a0 = *(const uint4*)(xrow + kt*32);
        uint4 a1 = *(const uint4*)(xrow + kt*32 + 4);
        short8 ahi, alo; unpack8(a0, a1, ahi, alo);
        short8 bhi = *(const short8*)&WxHi[(kq*KTX+kt)*512 + lane_off];
        short8 blo = *(const short8*)&WxLo[(kq*KTX+kt)*512 + lane_off];
        xacc = MFMA(ahi, bhi, xacc);
        xacc = MFMA(alo, bhi, xacc);
        xacc = MFMA(ahi, blo, xacc);
      }
    }
    // wait for h_t: wave 0 polls 4 flags/lane; others park at barrier
    if (t > 0) {
      if (wave == 0) {
        int f0,f1,f2,f3;
        do {
          f0 = ALOAD32(flags + lane);
          f1 = ALOAD32(flags + 64 + lane);
          f2 = ALOAD32(flags + 128 + lane);
          f3 = ALOAD32(flags + 192 + lane);
        } while (!__all(f0 >= t && f1 >= t && f2 >= t && f3 >= t));
      }
      __syncthreads();
    }
    { // recurrent: h(t) slice @ Wh tile
      const u32* hrow = hbuf + cur*32768 + (16*m + lo16)*1024 + kq*128 + hi16*8;
#pragma unroll
      for (int kt = 0; kt < KTH; ++kt) {
        const u64* hq = (const u64*)(hrow + kt*32);
        u64 q0 = ALOAD64(hq+0);
        u64 q1 = ALOAD64(hq+1);
        u64 q2 = ALOAD64(hq+2);
        u64 q3 = ALOAD64(hq+3);
        short8 ahi, alo; unpackq(q0,q1,q2,q3, ahi, alo);
        short8 bhi = *(const short8*)&WhHi[(kq*KTH+kt)*512 + lane_off];
        short8 blo = *(const short8*)&WhLo[(kq*KTH+kt)*512 + lane_off];
        racc = MFMA(ahi, bhi, racc);
        racc = MFMA(alo, bhi, racc);
        racc = MFMA(ahi, blo, racc);
      }
    }
    { // exchange partials: D layout col=lane&15, row=(lane>>4)*4+r
      const int bb = 16*m + hi16*4;
#pragma unroll
      for (int r4 = 0; r4 < 4; ++r4)
        exch[(kq*32 + bb + r4)*18 + lo16] = xacc[r4] + racc[r4];
    }
    __syncthreads();
    if (tid < 128) { // gates: one (b,unit) per thread
      float zp=0.f, rp=0.f, xh=0.f, rh=0.f;
#pragma unroll
      for (int q = 0; q < 8; ++q) {
        const float* e = &exch[(q*32 + eb)*18];
        zp += e[eu_l];
        rp += e[4 + eu_l];
        xh += e[8 + eu_l];
        rh += e[12 + eu_l];
      }
      float z = 1.f/(1.f + __expf(-(zp + zb)));
      float r = 1.f/(1.f + __expf(-(rp + rbv)));
      float pre = xh + hxb + r*(rh + hrb);
      float ex = __expf(-2.f*fabsf(pre));
      float th = (1.f - ex)/(1.f + ex);
      float hh = copysignf(th, pre);
      float hn = z*harr[tid] + (1.f - z)*hh;
      harr[tid] = hn;
      u32 pk = pack_f(hn);
      ASTORE32(hbuf + nxt*32768 + eb*1024 + u0 + eu_l, pk);
      if (LAYER==0) {
        if ((t & 3) == 0)
          out_pack[((size_t)(t>>2)*32 + eb)*1024 + u0 + eu_l] = pk;
      } else {
        out_pack[((size_t)t*32 + eb)*1024 + u0 + eu_l] = pk;
      }
    }
    asm volatile("s_waitcnt vmcnt(0)" ::: "memory");   // own stores acked
    __syncthreads();                                   // => whole WG's stores acked
    if (tid == 0)
      ASTORE32(flags + wg, t+1);
  }
}

// ---------------- final dense head ----------------
// h2 [250][32][1024] packed ; W [1024][41] ; out [32][250][41] f32
__global__ __launch_bounds__(256, 1)
void dense_k(const u32* __restrict__ h2, const float* __restrict__ W,
             const float* __restrict__ bias, float* __restrict__ out){
  __shared__ float rows[32*1025];
  const int ts = blockIdx.x;
  const u32* src = h2 + (size_t)ts*32768;
  for (int i = threadIdx.x; i < 32768; i += 256){
    u32 p = src[i];
    rows[(i>>10)*1025 + (i&1023)] = bf2f(p & 0xffffu) + bf2f(p >> 16);
  }
  __syncthreads();
  const int b = threadIdx.x >> 3, cg = threadIdx.x & 7;
  float acc[6] = {0.f,0.f,0.f,0.f,0.f,0.f};
  for (int k = 0; k < 1024; ++k){
    float hv = rows[b*1025 + k];
    const float* wr = W + k*41;
#pragma unroll
    for (int j = 0; j < 6; ++j){ int c = cg + 8*j; if (c < 41) acc[j] += hv*wr[c]; }
  }
#pragma unroll
  for (int j = 0; j < 6; ++j){
    int c = cg + 8*j;
    if (c < 41) out[((size_t)b*250 + ts)*41 + c] = acc[j] + bias[c];
  }
}

// ---------------- launch ----------------
extern "C" void kernel_launch(void* const* d_in, const int* in_sizes, int n_in,
                              void* d_out, int out_size, void* d_ws, size_t ws_size,
                              hipStream_t stream) {
  const float* x      = (const float*)d_in[0];
  const float* conv_w = (const float*)d_in[1];
  const float* h0i    = (const float*)d_in[2];
  const float* w0x    = (const float*)d_in[3];
  const float* w0h    = (const float*)d_in[4];
  const float* b0     = (const float*)d_in[5];
  const float* w1x    = (const float*)d_in[6];
  const float* w1h    = (const float*)d_in[7];
  const float* b1     = (const float*)d_in[8];
  const float* dw     = (const float*)d_in[9];
  const float* db     = (const float*)d_in[10];
  float* outp = (float*)d_out;

  if (ws_size < WS_NEED) return;  // workspace too small: leave output poisoned

  char* ws = (char*)d_ws;
  u32* y_pack   = (u32*)(ws + OFF_Y);
  u32* out2     = (u32*)(ws + OFF_Y);      // reuse after y_pack is dead
  u32* sub_pack = (u32*)(ws + OFF_SUB);
  u16* w0x_hi = (u16*)(ws + OFF_W0XH); u16* w0x_lo = (u16*)(ws + OFF_W0XL);
  u16* w0h_hi = (u16*)(ws + OFF_W0HH); u16* w0h_lo = (u16*)(ws + OFF_W0HL);
  u16* w1x_hi = (u16*)(ws + OFF_W1XH); u16* w1x_lo = (u16*)(ws + OFF_W1XL);
  u16* w1h_hi = (u16*)(ws + OFF_W1HH); u16* w1h_lo = (u16*)(ws + OFF_W1HL);
  u32* hb0 = (u32*)(ws + OFF_HB0);
  u32* hb1 = (u32*)(ws + OFF_HB1);
  int* fl0 = (int*)(ws + OFF_FL0);
  int* fl1 = (int*)(ws + OFF_FL1);

  init_state<<<64, 512, 0, stream>>>(h0i, hb0, hb1, fl0, fl1);
  build_frags<<<2048, 256, 0, stream>>>(w0x, w0x_hi, w0x_lo, 256);
  build_frags<<<2048, 256, 0, stream>>>(w0h, w0h_hi, w0h_lo, 1024);
  build_frags<<<2048, 256, 0, stream>>>(w1x, w1x_hi, w1x_lo, 1024);
  build_frags<<<2048, 256, 0, stream>>>(w1h, w1h_hi, w1h_lo, 1024);
  conv_pack<<<4096, 256, 0, stream>>>(x, conv_w, y_pack);

  gru_persist<0><<<256, 1024, 0, stream>>>(y_pack, w0x_hi, w0x_lo, w0h_hi, w0h_lo,
                                           b0, hb0, fl0, sub_pack);
  gru_persist<1><<<256, 1024, 0, stream>>>(sub_pack, w1x_hi, w1x_lo, w1h_hi, w1h_lo,
                                           b1, hb1, fl1, out2);

  dense_k<<<250, 256, 0, stream>>>(out2, dw, db, outp);
}